// Round 1
// baseline (84.707 us; speedup 1.0000x reference)
//
#include <hip/hip_runtime.h>

// Problem constants (match the JAX reference)
constexpr int T_LEN  = 1000;   // B*T, B=1
constexpr int NBKG   = 100;    // background units
constexpr int NV1    = 50000;
constexpr int NLM    = 10000;
constexpr int NPOST  = NV1 + NLM;   // 60000
constexpr int CONN   = 4;

constexpr int TCHUNK = 40;     // t steps per block (25 chunks of 40 = 1000)
constexpr int NPT    = 4;      // neurons per thread (float4 store)
constexpr int BLOCK  = 256;
constexpr int NPB    = BLOCK * NPT;  // 1024 neurons per block

__global__ __launch_bounds__(BLOCK)
void bkg_noise_kernel(const float* __restrict__ rest,      // [T_LEN, NBKG]
                      const float* __restrict__ v1_w,      // [NV1*CONN]
                      const int*   __restrict__ v1_c,      // [NV1*CONN]
                      const float* __restrict__ lm_w,      // [NLM*CONN]
                      const int*   __restrict__ lm_c,      // [NLM*CONN]
                      float* __restrict__ out)             // [T_LEN, NPOST]
{
    __shared__ float s_rest[TCHUNK * NBKG];   // 16 KB

    const int t0 = blockIdx.y * TCHUNK;

    // Cooperative staging of 40 rest rows (4000 floats) as float4, coalesced.
    {
        const float4* src = reinterpret_cast<const float4*>(rest + (size_t)t0 * NBKG);
        float4* dst = reinterpret_cast<float4*>(s_rest);
        for (int i = threadIdx.x; i < TCHUNK * NBKG / 4; i += BLOCK) dst[i] = src[i];
    }
    __syncthreads();

    const int n0 = blockIdx.x * NPB + threadIdx.x * NPT;
    if (n0 >= NPOST) return;

    // 50000 % 4 == 0 -> a thread's 4 neurons never straddle the v1/lm split.
    const float* wp;
    const int*   cp;
    if (n0 < NV1) { wp = v1_w + (size_t)n0 * CONN;          cp = v1_c + (size_t)n0 * CONN; }
    else          { wp = lm_w + (size_t)(n0 - NV1) * CONN;  cp = lm_c + (size_t)(n0 - NV1) * CONN; }

    // 16 contiguous weights + 16 contiguous cols per thread (coalesced across lanes).
    float wv[NPT * CONN];
    int   cv[NPT * CONN];
    {
        const float4* w4 = reinterpret_cast<const float4*>(wp);
        const int4*   c4 = reinterpret_cast<const int4*>(cp);
        #pragma unroll
        for (int i = 0; i < NPT; ++i) {
            float4 w = w4[i];
            int4   c = c4[i];
            wv[i*4+0] = w.x; wv[i*4+1] = w.y; wv[i*4+2] = w.z; wv[i*4+3] = w.w;
            cv[i*4+0] = c.x; cv[i*4+1] = c.y; cv[i*4+2] = c.z; cv[i*4+3] = c.w;
        }
    }

    for (int tt = 0; tt < TCHUNK; ++tt) {
        const float* __restrict__ rrow = s_rest + tt * NBKG;
        float4 o;
        float* op = reinterpret_cast<float*>(&o);
        #pragma unroll
        for (int j = 0; j < NPT; ++j) {
            float acc = wv[j*4+0] * rrow[cv[j*4+0]];
            acc = fmaf(wv[j*4+1], rrow[cv[j*4+1]], acc);
            acc = fmaf(wv[j*4+2], rrow[cv[j*4+2]], acc);
            acc = fmaf(wv[j*4+3], rrow[cv[j*4+3]], acc);
            op[j] = acc;
        }
        *reinterpret_cast<float4*>(out + (size_t)(t0 + tt) * NPOST + n0) = o;
    }
}

extern "C" void kernel_launch(void* const* d_in, const int* in_sizes, int n_in,
                              void* d_out, int out_size, void* d_ws, size_t ws_size,
                              hipStream_t stream) {
    // setup_inputs order: rest, v1_weights, v1_rows, v1_cols, lm_weights, lm_rows, lm_cols
    const float* rest = (const float*)d_in[0];
    const float* v1_w = (const float*)d_in[1];
    // d_in[2] = v1_rows (implicit: repeat(arange(NV1), CONN)) -- unused
    const int*   v1_c = (const int*)d_in[3];
    const float* lm_w = (const float*)d_in[4];
    // d_in[5] = lm_rows -- unused
    const int*   lm_c = (const int*)d_in[6];
    float* out = (float*)d_out;

    dim3 grid((NPOST + NPB - 1) / NPB, T_LEN / TCHUNK);  // 59 x 25
    bkg_noise_kernel<<<grid, BLOCK, 0, stream>>>(rest, v1_w, v1_c, lm_w, lm_c, out);
}

// Round 2
// 49.399 us; speedup vs baseline: 1.7147x; 1.7147x over previous
//
#include <hip/hip_runtime.h>

// Problem constants (match the JAX reference)
constexpr int T_LEN  = 1000;   // B*T, B=1
constexpr int NBKG   = 100;    // background units
constexpr int NV1    = 50000;
constexpr int NLM    = 10000;
constexpr int NPOST  = NV1 + NLM;   // 60000
constexpr int CONN   = 4;

constexpr int TCHUNK = 40;     // t steps per block (25 chunks of 40 = 1000)
constexpr int NPT    = 4;      // neurons per thread (float4 store)
constexpr int BLOCK  = 256;
constexpr int NPB    = BLOCK * NPT;  // 1024 neurons per block
constexpr int TSTRIDE = 44;    // padded t-stride (floats). 44*4=176 B, 16B-aligned;
                               // col*44 mod 32 = col*12 mod 32 -> 8 start classes
                               // exactly tiling all 32 banks with 4-bank b128 reads.

__global__ __launch_bounds__(BLOCK)
void bkg_noise_kernel(const float* __restrict__ rest,      // [T_LEN, NBKG]
                      const float* __restrict__ v1_w,      // [NV1*CONN]
                      const int*   __restrict__ v1_c,      // [NV1*CONN]
                      const float* __restrict__ lm_w,      // [NLM*CONN]
                      const int*   __restrict__ lm_c,      // [NLM*CONN]
                      float* __restrict__ out)             // [T_LEN, NPOST]
{
    // Transposed rest tile: s_restT[c * TSTRIDE + t] = rest[t0+t][c]
    __shared__ float s_restT[NBKG * TSTRIDE];   // 17.6 KB

    const int t0 = blockIdx.y * TCHUNK;

    // Stage + transpose. Global reads coalesced (consecutive idx -> consecutive addr);
    // LDS write conflicts only cost during this tiny phase (4000 words/block).
    for (int idx = threadIdx.x; idx < TCHUNK * NBKG; idx += BLOCK) {
        const int t = idx / NBKG;
        const int c = idx - t * NBKG;
        s_restT[c * TSTRIDE + t] = rest[(size_t)(t0 + t) * NBKG + c];
    }
    __syncthreads();

    const int n0 = blockIdx.x * NPB + threadIdx.x * NPT;
    if (n0 >= NPOST) return;

    // 50000 % 4 == 0 -> a thread's 4 neurons never straddle the v1/lm split.
    const float* wp;
    const int*   cp;
    if (n0 < NV1) { wp = v1_w + (size_t)n0 * CONN;          cp = v1_c + (size_t)n0 * CONN; }
    else          { wp = lm_w + (size_t)(n0 - NV1) * CONN;  cp = lm_c + (size_t)(n0 - NV1) * CONN; }

    // 16 contiguous weights + 16 contiguous cols per thread (coalesced across lanes).
    float wv[NPT * CONN];
    int   boff[NPT * CONN];    // precomputed LDS float-offsets: col * TSTRIDE
    {
        const float4* w4 = reinterpret_cast<const float4*>(wp);
        const int4*   c4 = reinterpret_cast<const int4*>(cp);
        #pragma unroll
        for (int i = 0; i < NPT; ++i) {
            float4 w = w4[i];
            int4   c = c4[i];
            wv[i*4+0] = w.x; wv[i*4+1] = w.y; wv[i*4+2] = w.z; wv[i*4+3] = w.w;
            boff[i*4+0] = c.x * TSTRIDE;
            boff[i*4+1] = c.y * TSTRIDE;
            boff[i*4+2] = c.z * TSTRIDE;
            boff[i*4+3] = c.w * TSTRIDE;
        }
    }

    // Main loop: 4 t-values per ds_read_b128 (column-major rest tile).
    #pragma unroll
    for (int t4 = 0; t4 < TCHUNK / 4; ++t4) {
        float acc[4][NPT];   // [t_sub][neuron]
        #pragma unroll
        for (int j = 0; j < NPT; ++j) {
            const float4 r0 = *reinterpret_cast<const float4*>(&s_restT[boff[j*4+0] + t4*4]);
            const float4 r1 = *reinterpret_cast<const float4*>(&s_restT[boff[j*4+1] + t4*4]);
            const float4 r2 = *reinterpret_cast<const float4*>(&s_restT[boff[j*4+2] + t4*4]);
            const float4 r3 = *reinterpret_cast<const float4*>(&s_restT[boff[j*4+3] + t4*4]);
            const float w0 = wv[j*4+0], w1 = wv[j*4+1], w2 = wv[j*4+2], w3 = wv[j*4+3];
            acc[0][j] = fmaf(w3, r3.x, fmaf(w2, r2.x, fmaf(w1, r1.x, w0 * r0.x)));
            acc[1][j] = fmaf(w3, r3.y, fmaf(w2, r2.y, fmaf(w1, r1.y, w0 * r0.y)));
            acc[2][j] = fmaf(w3, r3.z, fmaf(w2, r2.z, fmaf(w1, r1.z, w0 * r0.z)));
            acc[3][j] = fmaf(w3, r3.w, fmaf(w2, r2.w, fmaf(w1, r1.w, w0 * r0.w)));
        }
        #pragma unroll
        for (int t = 0; t < 4; ++t) {
            float4 o = make_float4(acc[t][0], acc[t][1], acc[t][2], acc[t][3]);
            *reinterpret_cast<float4*>(out + (size_t)(t0 + t4*4 + t) * NPOST + n0) = o;
        }
    }
}

extern "C" void kernel_launch(void* const* d_in, const int* in_sizes, int n_in,
                              void* d_out, int out_size, void* d_ws, size_t ws_size,
                              hipStream_t stream) {
    // setup_inputs order: rest, v1_weights, v1_rows, v1_cols, lm_weights, lm_rows, lm_cols
    const float* rest = (const float*)d_in[0];
    const float* v1_w = (const float*)d_in[1];
    // d_in[2] = v1_rows (implicit: repeat(arange(NV1), CONN)) -- unused
    const int*   v1_c = (const int*)d_in[3];
    const float* lm_w = (const float*)d_in[4];
    // d_in[5] = lm_rows -- unused
    const int*   lm_c = (const int*)d_in[6];
    float* out = (float*)d_out;

    dim3 grid((NPOST + NPB - 1) / NPB, T_LEN / TCHUNK);  // 59 x 25
    bkg_noise_kernel<<<grid, BLOCK, 0, stream>>>(rest, v1_w, v1_c, lm_w, lm_c, out);
}